// Round 19
// baseline (516.290 us; speedup 1.0000x reference)
//
#include <hip/hip_runtime.h>
#include <math.h>

#define NEG_SLOPE 0.2f
#define LN_EPS 1e-5f
#define BUCKET 48

typedef __attribute__((ext_vector_type(2))) float f32x2;

// DPP-based add: x += x permuted by CTRL (within 16-lane rows)
template <int CTRL>
__device__ __forceinline__ float dpp_add(float x) {
    int s = __builtin_amdgcn_update_dpp(0, __float_as_int(x), CTRL, 0xF, 0xF, true);
    return x + __int_as_float(s);
}
// full 16-lane row sum
__device__ __forceinline__ float row16_sum(float x) {
    x = dpp_add<0xB1>(x);   // quad_perm [1,0,3,2]
    x = dpp_add<0x4E>(x);   // quad_perm [2,3,0,1]
    x = dpp_add<0x124>(x);  // row_ror:4
    x = dpp_add<0x128>(x);  // row_ror:8
    return x;
}

// ---------- prep (FROZEN): transforms + hop fold + buckets ----------
__global__ __launch_bounds__(256) void prep(
    const float* __restrict__ x,
    const float* __restrict__ W_l, const float* __restrict__ b_l,
    const float* __restrict__ W_r, const float* __restrict__ b_r,
    const float* __restrict__ W_res, const float* __restrict__ b_res,
    const float* __restrict__ W_e,
    const int* __restrict__ dist, const float* __restrict__ bph,
    float* __restrict__ xl, float* __restrict__ xr, float* __restrict__ xres_out,
    const int* __restrict__ ei, int* __restrict__ counts, int2* __restrict__ bucket,
    int n, int E_) {
    __shared__ float sWl[4096];
    __shared__ float sWr[4096];
    __shared__ float sWs[4096];
    __shared__ float sx[256];
    for (int i = threadIdx.x; i < 4096; i += 256) {
        sWl[i] = W_l[i]; sWr[i] = W_r[i]; sWs[i] = W_res[i];
    }
    int lane = threadIdx.x & 63;
    int w = threadIdx.x >> 6;
    float bl = b_l[lane], br = b_r[lane], bs = b_res[lane];
    float wsum = 0.0f;
#pragma unroll
    for (int k = 0; k < 16; ++k) wsum += W_e[k * 64 + lane];
    __syncthreads();
    for (int base = blockIdx.x * 4; base < n; base += gridDim.x * 4) {
        __syncthreads();
        int r = base + w;
        if (r < n) sx[threadIdx.x] = x[(size_t)r * 64 + lane];
        __syncthreads();
        if (r < n) {
            float al = bl, ar = br, as_ = bs;
            const float* xv = &sx[w * 64];
#pragma unroll
            for (int k = 0; k < 64; ++k) {
                float xk = xv[k];
                al = fmaf(xk, sWl[k * 64 + lane], al);
                ar = fmaf(xk, sWr[k * 64 + lane], ar);
                as_ = fmaf(xk, sWs[k * 64 + lane], as_);
            }
            int hop = dist[r];
            hop = hop < 0 ? 0 : (hop > 3 ? 3 : hop);
            float hb = 0.1f * bph[hop];
            xl[(size_t)r * 64 + lane] = al;
            xr[(size_t)r * 64 + lane] = fmaf(hb, wsum, ar);  // hop bias folded in
            xres_out[(size_t)r * 64 + lane] = as_;           // residual staged in d_out
        }
    }
    // direct bucket placement
    const int* di = ei + E_;
    for (int e = blockIdx.x * 256 + threadIdx.x; e < E_; e += gridDim.x * 256) {
        int dst = di[e];
        int src = ei[e];
        int pos = atomicAdd(&counts[dst], 1);
        pos = pos < BUCKET - 1 ? pos : BUCKET - 1;  // safety clamp
        bucket[(size_t)dst * BUCKET + pos] = make_int2(e, src);
    }
}

// ---------- pass 1: edge logits in e-order (sequential streams, deep prefetch) ------
#define CL(J) ((J) > last ? last : (J))

#define LLOAD_G(G, EE)                                                      \
    {                                                                       \
        const f32x2* p = (const f32x2*)(eattr + (size_t)(EE) * 16);         \
        _Pragma("unroll") for (int k = 0; k < 8; ++k) G[k] = p[k];          \
    }

// consume edge j with (G,X); store ex; refill G,X for j+3; sd for j+6
#define LPHASE(G, X, SS, DD, J)                                             \
    {                                                                       \
        f32x2 mm; mm.x = X; mm.y = 0.0f;                                    \
        _Pragma("unroll") for (int k = 0; k < 8; ++k)                       \
            mm = __builtin_elementwise_fma(G[k], w2[k], mm);                \
        float m = mm.x + mm.y;                                              \
        m = fmaxf(m, NEG_SLOPE * m);                                        \
        float l = row16_sum(m * attv);                                      \
        float ex = __builtin_amdgcn_exp2f(l);                               \
        if ((J) < len && (lane & 15) == 0)                                  \
            exv[(size_t)(eb + (J)) * 4 + (lane >> 4)] = ex;                 \
        int nj = CL((J) + 3);                                               \
        LLOAD_G(G, eb + nj);                                                \
        X = xl[((unsigned)SS << 6) | lane] + xr[((unsigned)DD << 6) | lane];\
        int fj = eb + CL((J) + 6);                                          \
        SS = ei[fj];                                                        \
        DD = ei[E_ + fj];                                                   \
    }

__global__ __launch_bounds__(256) void edge_logits(
    const int* __restrict__ ei, const float* __restrict__ eattr,
    const float* __restrict__ W_e, const float* __restrict__ att,
    const float* __restrict__ xl, const float* __restrict__ xr,
    float* __restrict__ exv, int E_) {
    int lane = threadIdx.x & 63;
    float attv = att[lane] * 1.44269504f;  // log2(e) folded: exp -> exp2
    f32x2 w2[8];
#pragma unroll
    for (int k = 0; k < 8; ++k) {
        w2[k].x = W_e[(2 * k) * 64 + lane];
        w2[k].y = W_e[(2 * k + 1) * 64 + lane];
    }
    int wid = (blockIdx.x * blockDim.x + threadIdx.x) >> 6;
    int nw = (gridDim.x * blockDim.x) >> 6;
    int chunk = (E_ + nw - 1) / nw;
    int e0 = wid * chunk;
    int e1 = e0 + chunk; if (e1 > E_) e1 = E_;
    if (e0 >= e1) return;
    int eb = __builtin_amdgcn_readfirstlane(e0);  // scalarize the whole stream
    int len = e1 - e0;
    int last = len - 1;
    // prologue: edges 0,1,2 (clamped) + sd for 3,4,5
    int sA, dA, sB, dB, sC, dC;
    float X0, X1, X2;
    f32x2 G0[8], G1[8], G2[8];
    {
        int ja = 0, jb = CL(1), jc = CL(2);
        int s0_ = ei[eb + ja], d0_ = ei[E_ + eb + ja];
        int s1_ = ei[eb + jb], d1_ = ei[E_ + eb + jb];
        int s2_ = ei[eb + jc], d2_ = ei[E_ + eb + jc];
        X0 = xl[((unsigned)s0_ << 6) | lane] + xr[((unsigned)d0_ << 6) | lane];
        X1 = xl[((unsigned)s1_ << 6) | lane] + xr[((unsigned)d1_ << 6) | lane];
        X2 = xl[((unsigned)s2_ << 6) | lane] + xr[((unsigned)d2_ << 6) | lane];
        LLOAD_G(G0, eb + ja);
        LLOAD_G(G1, eb + jb);
        LLOAD_G(G2, eb + jc);
        int j3 = eb + CL(3), j4 = eb + CL(4), j5 = eb + CL(5);
        sA = ei[j3]; dA = ei[E_ + j3];
        sB = ei[j4]; dB = ei[E_ + j4];
        sC = ei[j5]; dC = ei[E_ + j5];
    }
    for (int j = 0; j < len; j += 3) {
        LPHASE(G0, X0, sA, dA, j)
        LPHASE(G1, X1, sB, dB, j + 1)
        LPHASE(G2, X2, sC, dC, j + 2)
    }
}

// ---------- pass 2: light gather + softmax divide + LN + residual ----------
#define GPHASE(EX, X, B, F, DEN, ACC, I)                                    \
    {                                                                       \
        float ex = (I) < cnt ? EX : 0.0f;                                   \
        DEN += ex;                                                          \
        ACC = fmaf(ex, X, ACC);                                             \
        X = xl[((unsigned)(B).y << 6) | lane];                              \
        EX = exv[(((unsigned)(B).x) << 2) + hsel];                          \
        B = F;                                                              \
        int nx = (I) + 9; nx = nx > lastj ? lastj : nx;                     \
        F = bk[nx];                                                         \
    }

__global__ __launch_bounds__(256) void gather_ln(
    const int* __restrict__ counts, const int2* __restrict__ bucket,
    const float* __restrict__ exv, const float* __restrict__ xl,
    const float* __restrict__ bias,
    const float* __restrict__ gamma, const float* __restrict__ beta,
    float* out, int n) {
    int lane = threadIdx.x & 63;
    unsigned hsel = lane >> 4;
    float bi = bias[lane], g = gamma[lane], be = beta[lane];
    int wid = (blockIdx.x * blockDim.x + threadIdx.x) >> 6;
    int nw = (gridDim.x * blockDim.x) >> 6;
    for (int r = wid; r < n; r += nw) {
        int cnt = counts[r];
        float den0 = 0.0f, den1 = 0.0f, den2 = 0.0f;
        float acc0 = 0.0f, acc1 = 0.0f, acc2 = 0.0f;
        if (cnt > 0) {
            cnt = cnt < BUCKET ? cnt : BUCKET;
            const int2* bk = bucket + (size_t)r * BUCKET;
            int lastj = cnt - 1;
            int j1 = 1 > lastj ? lastj : 1;
            int j2 = 2 > lastj ? lastj : 2;
            int j3 = 3 > lastj ? lastj : 3;
            int j4 = 4 > lastj ? lastj : 4;
            int j5 = 5 > lastj ? lastj : 5;
            int j6 = 6 > lastj ? lastj : 6;
            int j7 = 7 > lastj ? lastj : 7;
            int j8 = 8 > lastj ? lastj : 8;
            int2 b0 = bk[0];
            int2 b1 = bk[j1];
            int2 b2 = bk[j2];
            int2 B0 = bk[j3];
            int2 B1 = bk[j4];
            int2 B2 = bk[j5];
            int2 F0 = bk[j6];
            int2 F1 = bk[j7];
            int2 F2 = bk[j8];
            float X0 = xl[((unsigned)b0.y << 6) | lane];
            float X1 = xl[((unsigned)b1.y << 6) | lane];
            float X2 = xl[((unsigned)b2.y << 6) | lane];
            float EX0 = exv[(((unsigned)b0.x) << 2) + hsel];
            float EX1 = exv[(((unsigned)b1.x) << 2) + hsel];
            float EX2 = exv[(((unsigned)b2.x) << 2) + hsel];
            for (int i = 0; i < cnt; i += 3) {
                GPHASE(EX0, X0, B0, F0, den0, acc0, i)
                GPHASE(EX1, X1, B1, F1, den1, acc1, i + 1)
                GPHASE(EX2, X2, B2, F2, den2, acc2, i + 2)
            }
        }
        float den = (den0 + den1) + den2;
        float acc = (acc0 + acc1) + acc2;
        float v = acc / (den + 1e-16f) + bi;
        // LayerNorm over 64 features
        float s = row16_sum(v);
        s += __shfl_xor(s, 16, 64);
        s += __shfl_xor(s, 32, 64);
        float mu = s * (1.0f / 64.0f);
        float dd = v - mu;
        float q = row16_sum(dd * dd);
        q += __shfl_xor(q, 16, 64);
        q += __shfl_xor(q, 32, 64);
        float var = q * (1.0f / 64.0f);
        float nv = dd * rsqrtf(var + LN_EPS) * g + be;
        unsigned idx = ((unsigned)r << 6) | lane;
        out[idx] = nv + out[idx];  // residual was staged in out by prep
    }
}

extern "C" void kernel_launch(void* const* d_in, const int* in_sizes, int n_in,
                              void* d_out, int out_size, void* d_ws, size_t ws_size,
                              hipStream_t stream) {
    const float* x     = (const float*)d_in[0];
    const int*   ei    = (const int*)d_in[1];
    const float* eattr = (const float*)d_in[2];
    const int*   dist  = (const int*)d_in[3];
    const float* W_l   = (const float*)d_in[4];
    const float* b_l   = (const float*)d_in[5];
    const float* W_r   = (const float*)d_in[6];
    const float* b_r   = (const float*)d_in[7];
    const float* W_e   = (const float*)d_in[8];
    const float* att   = (const float*)d_in[9];
    const float* bias  = (const float*)d_in[10];
    const float* gamma = (const float*)d_in[11];
    const float* beta  = (const float*)d_in[12];
    const float* W_res = (const float*)d_in[13];
    const float* b_res = (const float*)d_in[14];
    const float* bph   = (const float*)d_in[15];

    int n  = in_sizes[0] / 64;
    int E_ = in_sizes[1] / 2;
    float* out = (float*)d_out;

    char* ws = (char*)d_ws;
    float* xl     = (float*)ws; ws += (size_t)n * 64 * 4;
    float* xr     = (float*)ws; ws += (size_t)n * 64 * 4;
    int2*  bucket = (int2*)ws;  ws += (size_t)n * BUCKET * 8;
    float* exv    = (float*)ws; ws += (size_t)E_ * 4 * 4;
    int*   counts = (int*)ws;   ws += (size_t)n * 4;

    hipMemsetAsync(counts, 0, (size_t)n * 4, stream);
    prep<<<2048, 256, 0, stream>>>(x, W_l, b_l, W_r, b_r, W_res, b_res, W_e,
                                   dist, bph, xl, xr, out, ei, counts, bucket, n, E_);
    edge_logits<<<4096, 256, 0, stream>>>(ei, eattr, W_e, att, xl, xr, exv, E_);
    gather_ln<<<4096, 256, 0, stream>>>(counts, bucket, exv, xl,
                                        bias, gamma, beta, out, n);
}

// Round 20
// 318.696 us; speedup vs baseline: 1.6200x; 1.6200x over previous
//
#include <hip/hip_runtime.h>
#include <math.h>

#define NEG_SLOPE 0.2f
#define LN_EPS 1e-5f
#define BUCKET 48

typedef __attribute__((ext_vector_type(2))) float f32x2;
typedef const float __attribute__((address_space(1))) gf32;
typedef float __attribute__((address_space(3))) lf32;

// DPP-based add: x += x permuted by CTRL (within 16-lane rows)
template <int CTRL>
__device__ __forceinline__ float dpp_add(float x) {
    int s = __builtin_amdgcn_update_dpp(0, __float_as_int(x), CTRL, 0xF, 0xF, true);
    return x + __int_as_float(s);
}
// full 16-lane row sum
__device__ __forceinline__ float row16_sum(float x) {
    x = dpp_add<0xB1>(x);   // quad_perm [1,0,3,2]
    x = dpp_add<0x4E>(x);   // quad_perm [2,3,0,1]
    x = dpp_add<0x124>(x);  // row_ror:4
    x = dpp_add<0x128>(x);  // row_ror:8
    return x;
}

// ---------- prep (FROZEN): transforms + hop fold + buckets ----------
__global__ __launch_bounds__(256) void prep(
    const float* __restrict__ x,
    const float* __restrict__ W_l, const float* __restrict__ b_l,
    const float* __restrict__ W_r, const float* __restrict__ b_r,
    const float* __restrict__ W_res, const float* __restrict__ b_res,
    const float* __restrict__ W_e,
    const int* __restrict__ dist, const float* __restrict__ bph,
    float* __restrict__ xl, float* __restrict__ xr, float* __restrict__ xres_out,
    const int* __restrict__ ei, int* __restrict__ counts, int2* __restrict__ bucket,
    int n, int E_) {
    __shared__ float sWl[4096];
    __shared__ float sWr[4096];
    __shared__ float sWs[4096];
    __shared__ float sx[256];
    for (int i = threadIdx.x; i < 4096; i += 256) {
        sWl[i] = W_l[i]; sWr[i] = W_r[i]; sWs[i] = W_res[i];
    }
    int lane = threadIdx.x & 63;
    int w = threadIdx.x >> 6;
    float bl = b_l[lane], br = b_r[lane], bs = b_res[lane];
    float wsum = 0.0f;
#pragma unroll
    for (int k = 0; k < 16; ++k) wsum += W_e[k * 64 + lane];
    __syncthreads();
    for (int base = blockIdx.x * 4; base < n; base += gridDim.x * 4) {
        __syncthreads();
        int r = base + w;
        if (r < n) sx[threadIdx.x] = x[(size_t)r * 64 + lane];
        __syncthreads();
        if (r < n) {
            float al = bl, ar = br, as_ = bs;
            const float* xv = &sx[w * 64];
#pragma unroll
            for (int k = 0; k < 64; ++k) {
                float xk = xv[k];
                al = fmaf(xk, sWl[k * 64 + lane], al);
                ar = fmaf(xk, sWr[k * 64 + lane], ar);
                as_ = fmaf(xk, sWs[k * 64 + lane], as_);
            }
            int hop = dist[r];
            hop = hop < 0 ? 0 : (hop > 3 ? 3 : hop);
            float hb = 0.1f * bph[hop];
            xl[(size_t)r * 64 + lane] = al;
            xr[(size_t)r * 64 + lane] = fmaf(hb, wsum, ar);  // hop bias folded in
            xres_out[(size_t)r * 64 + lane] = as_;           // residual staged in d_out
        }
    }
    // direct bucket placement
    const int* di = ei + E_;
    for (int e = blockIdx.x * 256 + threadIdx.x; e < E_; e += gridDim.x * 256) {
        int dst = di[e];
        int src = ei[e];
        int pos = atomicAdd(&counts[dst], 1);
        pos = pos < BUCKET - 1 ? pos : BUCKET - 1;  // safety clamp
        bucket[(size_t)dst * BUCKET + pos] = make_int2(e, src);
    }
}

// ---------- fused gather: eattr via global_load_lds (vector path, in-order vmcnt) ----
// batch = 4 edges; one width-4 global_load_lds moves 4 eattr rows (256B) to LDS;
// 2-phase ping-pong over two DISTINCT shared arrays (alias-analyzable waits).

// load 4 bucket entries of batch BB (clamped)
#define RLOAD(R, BB)                                                        \
    {                                                                       \
        int i0 = (BB) * 4;                                                  \
        int k0 = i0 + 0 > last ? last : i0 + 0;                             \
        int k1 = i0 + 1 > last ? last : i0 + 1;                             \
        int k2 = i0 + 2 > last ? last : i0 + 2;                             \
        int k3 = i0 + 3 > last ? last : i0 + 3;                             \
        R[0] = bk[k0]; R[1] = bk[k1]; R[2] = bk[k2]; R[3] = bk[k3];         \
    }

// one global_load_lds: lane (i>>4) picks edge R[i>>4].x, (i&15) picks element
#define ISSUE_GLDS(S, R)                                                    \
    {                                                                       \
        int e0 = R[0].x, e1 = R[1].x, e2 = R[2].x, e3 = R[3].x;             \
        int eh = (lane & 16) ? e1 : e0;                                     \
        int el = (lane & 16) ? e3 : e2;                                     \
        int es = (lane & 32) ? el : eh;                                     \
        const float* gp = eattr + (size_t)(unsigned)es * 16 + (lane & 15);  \
        __builtin_amdgcn_global_load_lds((gf32*)gp, (lf32*)&S[w][0], 4, 0, 0); \
    }

#define XLOAD(X, R)                                                         \
    X[0] = xl[((unsigned)R[0].y << 6) | lane];                              \
    X[1] = xl[((unsigned)R[1].y << 6) | lane];                              \
    X[2] = xl[((unsigned)R[2].y << 6) | lane];                              \
    X[3] = xl[((unsigned)R[3].y << 6) | lane];

// consume 4 edges of batch I from slot S (X holds xl rows), then prefetch batch I+2
#define PHASE(S, R, X, DEN, ACC, I)                                         \
    {                                                                       \
        _Pragma("unroll")                                                   \
        for (int j = 0; j < 4; ++j) {                                       \
            const float4* p = (const float4*)&S[w][j * 16];                 \
            float4 qa = p[0], qb = p[1], qc = p[2], qd = p[3];              \
            f32x2 mm; mm.x = X[j] + base; mm.y = 0.0f;                      \
            f32x2 t;                                                        \
            t.x = qa.x; t.y = qa.y; mm = __builtin_elementwise_fma(t, w2[0], mm); \
            t.x = qa.z; t.y = qa.w; mm = __builtin_elementwise_fma(t, w2[1], mm); \
            t.x = qb.x; t.y = qb.y; mm = __builtin_elementwise_fma(t, w2[2], mm); \
            t.x = qb.z; t.y = qb.w; mm = __builtin_elementwise_fma(t, w2[3], mm); \
            t.x = qc.x; t.y = qc.y; mm = __builtin_elementwise_fma(t, w2[4], mm); \
            t.x = qc.z; t.y = qc.w; mm = __builtin_elementwise_fma(t, w2[5], mm); \
            t.x = qd.x; t.y = qd.y; mm = __builtin_elementwise_fma(t, w2[6], mm); \
            t.x = qd.z; t.y = qd.w; mm = __builtin_elementwise_fma(t, w2[7], mm); \
            float m = mm.x + mm.y;                                          \
            m = fmaxf(m, NEG_SLOPE * m);                                    \
            float l = row16_sum(m * attv);                                  \
            l = (4 * (I) + j) < cnt ? l : -1e30f;                           \
            float ex = __builtin_amdgcn_exp2f(l);                           \
            DEN += ex;                                                      \
            ACC = fmaf(ex, X[j], ACC);                                      \
        }                                                                   \
        ISSUE_GLDS(S, R)        /* batch I+2 into this slot (just drained) */\
        XLOAD(X, R)             /* xl rows for batch I+2 */                 \
        RLOAD(R, (I) + 4)       /* bucket entries for batch I+4 */          \
    }

__global__ __launch_bounds__(256) void fused_gather(
    const int* __restrict__ counts, const int2* __restrict__ bucket,
    const float* __restrict__ eattr,
    const float* __restrict__ W_e, const float* __restrict__ att,
    const float* __restrict__ xl, const float* __restrict__ xr,
    const float* __restrict__ bias,
    const float* __restrict__ gamma, const float* __restrict__ beta,
    float* out, int n) {
    __shared__ __align__(16) float sl0[4][64];
    __shared__ __align__(16) float sl1[4][64];
    int lane = threadIdx.x & 63;
    int w = threadIdx.x >> 6;
    float attv = att[lane] * 1.44269504f;  // log2(e) folded: exp -> exp2
    float bi = bias[lane], g = gamma[lane], be = beta[lane];
    f32x2 w2[8];
#pragma unroll
    for (int k = 0; k < 8; ++k) {
        w2[k].x = W_e[(2 * k) * 64 + lane];
        w2[k].y = W_e[(2 * k + 1) * 64 + lane];
    }

    int wid = (blockIdx.x * blockDim.x + threadIdx.x) >> 6;
    int nw = (gridDim.x * blockDim.x) >> 6;
    for (int r = wid; r < n; r += nw) {
        int cnt = counts[r];
        float den0 = 0.0f, den1 = 0.0f;
        float acc0 = 0.0f, acc1 = 0.0f;
        if (cnt > 0) {
            cnt = cnt < BUCKET ? cnt : BUCKET;
            float base = xr[((unsigned)r << 6) | lane];  // hop bias pre-folded
            const int2* bk = bucket + (size_t)r * BUCKET;
            int last = cnt - 1;
            int B = (cnt + 3) >> 2;
            int2 R0[4], R1[4];
            float X0[4], X1[4];
            RLOAD(R0, 0)
            RLOAD(R1, 1)
            ISSUE_GLDS(sl0, R0)
            ISSUE_GLDS(sl1, R1)
            XLOAD(X0, R0)
            XLOAD(X1, R1)
            RLOAD(R0, 2)
            RLOAD(R1, 3)
            for (int i = 0; i < B; i += 2) {
                PHASE(sl0, R0, X0, den0, acc0, i)
                PHASE(sl1, R1, X1, den1, acc1, i + 1)
            }
        }
        float den = den0 + den1;
        float acc = acc0 + acc1;
        float v = acc / (den + 1e-16f) + bi;
        // LayerNorm over 64 features
        float s = row16_sum(v);
        s += __shfl_xor(s, 16, 64);
        s += __shfl_xor(s, 32, 64);
        float mu = s * (1.0f / 64.0f);
        float dd = v - mu;
        float q = row16_sum(dd * dd);
        q += __shfl_xor(q, 16, 64);
        q += __shfl_xor(q, 32, 64);
        float var = q * (1.0f / 64.0f);
        float nv = dd * rsqrtf(var + LN_EPS) * g + be;
        unsigned idx = ((unsigned)r << 6) | lane;
        out[idx] = nv + out[idx];  // residual was staged in out by prep
    }
}

extern "C" void kernel_launch(void* const* d_in, const int* in_sizes, int n_in,
                              void* d_out, int out_size, void* d_ws, size_t ws_size,
                              hipStream_t stream) {
    const float* x     = (const float*)d_in[0];
    const int*   ei    = (const int*)d_in[1];
    const float* eattr = (const float*)d_in[2];
    const int*   dist  = (const int*)d_in[3];
    const float* W_l   = (const float*)d_in[4];
    const float* b_l   = (const float*)d_in[5];
    const float* W_r   = (const float*)d_in[6];
    const float* b_r   = (const float*)d_in[7];
    const float* W_e   = (const float*)d_in[8];
    const float* att   = (const float*)d_in[9];
    const float* bias  = (const float*)d_in[10];
    const float* gamma = (const float*)d_in[11];
    const float* beta  = (const float*)d_in[12];
    const float* W_res = (const float*)d_in[13];
    const float* b_res = (const float*)d_in[14];
    const float* bph   = (const float*)d_in[15];

    int n  = in_sizes[0] / 64;
    int E_ = in_sizes[1] / 2;
    float* out = (float*)d_out;

    char* ws = (char*)d_ws;
    float* xl     = (float*)ws; ws += (size_t)n * 64 * 4;
    float* xr     = (float*)ws; ws += (size_t)n * 64 * 4;
    int2*  bucket = (int2*)ws;  ws += (size_t)n * BUCKET * 8;
    int*   counts = (int*)ws;   ws += (size_t)n * 4;

    hipMemsetAsync(counts, 0, (size_t)n * 4, stream);
    prep<<<2048, 256, 0, stream>>>(x, W_l, b_l, W_r, b_r, W_res, b_res, W_e,
                                   dist, bph, xl, xr, out, ei, counts, bucket, n, E_);
    fused_gather<<<4096, 256, 0, stream>>>(counts, bucket, eattr,
                                           W_e, att, xl, xr,
                                           bias, gamma, beta, out, n);
}

// Round 21
// 281.381 us; speedup vs baseline: 1.8348x; 1.1326x over previous
//
#include <hip/hip_runtime.h>
#include <math.h>

#define NEG_SLOPE 0.2f
#define LN_EPS 1e-5f
#define BUCKET 48

typedef __attribute__((ext_vector_type(2))) float f32x2;

// DPP-based add: x += x permuted by CTRL (within 16-lane rows)
template <int CTRL>
__device__ __forceinline__ float dpp_add(float x) {
    int s = __builtin_amdgcn_update_dpp(0, __float_as_int(x), CTRL, 0xF, 0xF, true);
    return x + __int_as_float(s);
}
// full 16-lane row sum
__device__ __forceinline__ float row16_sum(float x) {
    x = dpp_add<0xB1>(x);   // quad_perm [1,0,3,2]
    x = dpp_add<0x4E>(x);   // quad_perm [2,3,0,1]
    x = dpp_add<0x124>(x);  // row_ror:4
    x = dpp_add<0x128>(x);  // row_ror:8
    return x;
}

// ---------- prep (FROZEN): transforms + hop-bias fold + direct bucket placement ------
__global__ __launch_bounds__(256) void prep(
    const float* __restrict__ x,
    const float* __restrict__ W_l, const float* __restrict__ b_l,
    const float* __restrict__ W_r, const float* __restrict__ b_r,
    const float* __restrict__ W_res, const float* __restrict__ b_res,
    const float* __restrict__ W_e,
    const int* __restrict__ dist, const float* __restrict__ bph,
    float* __restrict__ xl, float* __restrict__ xr, float* __restrict__ xres_out,
    const int* __restrict__ ei, int* __restrict__ counts, int2* __restrict__ bucket,
    int n, int E_) {
    __shared__ float sWl[4096];
    __shared__ float sWr[4096];
    __shared__ float sWs[4096];
    __shared__ float sx[256];
    for (int i = threadIdx.x; i < 4096; i += 256) {
        sWl[i] = W_l[i]; sWr[i] = W_r[i]; sWs[i] = W_res[i];
    }
    int lane = threadIdx.x & 63;
    int w = threadIdx.x >> 6;
    float bl = b_l[lane], br = b_r[lane], bs = b_res[lane];
    float wsum = 0.0f;
#pragma unroll
    for (int k = 0; k < 16; ++k) wsum += W_e[k * 64 + lane];
    __syncthreads();
    for (int base = blockIdx.x * 4; base < n; base += gridDim.x * 4) {
        __syncthreads();
        int r = base + w;
        if (r < n) sx[threadIdx.x] = x[(size_t)r * 64 + lane];
        __syncthreads();
        if (r < n) {
            float al = bl, ar = br, as_ = bs;
            const float* xv = &sx[w * 64];
#pragma unroll
            for (int k = 0; k < 64; ++k) {
                float xk = xv[k];
                al = fmaf(xk, sWl[k * 64 + lane], al);
                ar = fmaf(xk, sWr[k * 64 + lane], ar);
                as_ = fmaf(xk, sWs[k * 64 + lane], as_);
            }
            int hop = dist[r];
            hop = hop < 0 ? 0 : (hop > 3 ? 3 : hop);
            float hb = 0.1f * bph[hop];
            xl[(size_t)r * 64 + lane] = al;
            xr[(size_t)r * 64 + lane] = fmaf(hb, wsum, ar);  // hop bias folded in
            xres_out[(size_t)r * 64 + lane] = as_;           // residual staged in d_out
        }
    }
    // direct bucket placement
    const int* di = ei + E_;
    for (int e = blockIdx.x * 256 + threadIdx.x; e < E_; e += gridDim.x * 256) {
        int dst = di[e];
        int src = ei[e];
        int pos = atomicAdd(&counts[dst], 1);
        pos = pos < BUCKET - 1 ? pos : BUCKET - 1;  // safety clamp
        bucket[(size_t)dst * BUCKET + pos] = make_int2(e, src);
    }
}

// ---------- fused gather: 3-phase rotating pipeline, no-max softmax (R15 form) -------
#define LOAD_G(G, EA)                                                       \
    {                                                                       \
        int ec = __builtin_amdgcn_readfirstlane((EA).x);                    \
        const f32x2* p = (const f32x2*)(eattr + (size_t)ec * 16);           \
        _Pragma("unroll") for (int k = 0; k < 8; ++k) G[k] = p[k];          \
    }

#define PHASE(G, X, E, DEN, ACC, I)                                         \
    {                                                                       \
        f32x2 mm; mm.x = X + base; mm.y = 0.0f;                             \
        _Pragma("unroll") for (int k = 0; k < 8; ++k)                       \
            mm = __builtin_elementwise_fma(G[k], w2[k], mm);                \
        float m = mm.x + mm.y;                                              \
        m = fmaxf(m, NEG_SLOPE * m);                                        \
        float l = row16_sum(m * attv);   /* attv pre-scaled by log2(e) */   \
        l = (I) < cnt ? l : -1e30f;                                         \
        float ex = __builtin_amdgcn_exp2f(l);                               \
        DEN += ex;                                                          \
        ACC = fmaf(ex, X, ACC);                                             \
        X = xl[((unsigned)(E).y << 6) | lane];                              \
        LOAD_G(G, E);                                                       \
        int nx = (I) + 6; nx = nx > last ? last : nx;                       \
        E = bk[nx];                                                         \
    }

__global__ __launch_bounds__(256) void fused_gather(
    const int* __restrict__ counts, const int2* __restrict__ bucket,
    const float* __restrict__ eattr,
    const float* __restrict__ W_e, const float* __restrict__ att,
    const float* __restrict__ xl, const float* __restrict__ xr,
    const float* __restrict__ bias,
    const float* __restrict__ gamma, const float* __restrict__ beta,
    float* out, int n) {
    int lane = threadIdx.x & 63;
    float attv = att[lane] * 1.44269504f;  // log2(e) folded: exp -> exp2
    float bi = bias[lane], g = gamma[lane], be = beta[lane];
    f32x2 w2[8];
#pragma unroll
    for (int k = 0; k < 8; ++k) {
        w2[k].x = W_e[(2 * k) * 64 + lane];
        w2[k].y = W_e[(2 * k + 1) * 64 + lane];
    }

    int wid = (blockIdx.x * blockDim.x + threadIdx.x) >> 6;
    int nw = (gridDim.x * blockDim.x) >> 6;
    for (int r = wid; r < n; r += nw) {
        int cnt = counts[r];            // vector load, r stays divergent
        float den0 = 0.0f, den1 = 0.0f, den2 = 0.0f;
        float acc0 = 0.0f, acc1 = 0.0f, acc2 = 0.0f;
        if (cnt > 0) {
            cnt = cnt < BUCKET ? cnt : BUCKET;
            float base = xr[((unsigned)r << 6) | lane];  // hop bias pre-folded
            const int2* bk = bucket + (size_t)r * BUCKET;
            int last = cnt - 1;
            int i1 = 1 > last ? last : 1;
            int i2 = 2 > last ? last : 2;
            int i3 = 3 > last ? last : 3;
            int i4 = 4 > last ? last : 4;
            int i5 = 5 > last ? last : 5;
            int2 A0 = bk[0];
            int2 A1 = bk[i1];
            int2 A2 = bk[i2];
            int2 E0 = bk[i3];
            int2 E1 = bk[i4];
            int2 E2 = bk[i5];
            float X0 = xl[((unsigned)A0.y << 6) | lane];
            float X1 = xl[((unsigned)A1.y << 6) | lane];
            float X2 = xl[((unsigned)A2.y << 6) | lane];
            f32x2 G0[8], G1[8], G2[8];
            LOAD_G(G0, A0);
            LOAD_G(G1, A1);
            LOAD_G(G2, A2);
            for (int i = 0; i < cnt; i += 3) {
                PHASE(G0, X0, E0, den0, acc0, i)
                PHASE(G1, X1, E1, den1, acc1, i + 1)
                PHASE(G2, X2, E2, den2, acc2, i + 2)
            }
        }
        float den = (den0 + den1) + den2;
        float acc = (acc0 + acc1) + acc2;
        float v = acc / (den + 1e-16f) + bi;
        // LayerNorm over 64 features
        float s = row16_sum(v);
        s += __shfl_xor(s, 16, 64);
        s += __shfl_xor(s, 32, 64);
        float mu = s * (1.0f / 64.0f);
        float dd = v - mu;
        float q = row16_sum(dd * dd);
        q += __shfl_xor(q, 16, 64);
        q += __shfl_xor(q, 32, 64);
        float var = q * (1.0f / 64.0f);
        float nv = dd * rsqrtf(var + LN_EPS) * g + be;
        unsigned idx = ((unsigned)r << 6) | lane;
        out[idx] = nv + out[idx];  // residual was staged in out by prep
    }
}

extern "C" void kernel_launch(void* const* d_in, const int* in_sizes, int n_in,
                              void* d_out, int out_size, void* d_ws, size_t ws_size,
                              hipStream_t stream) {
    const float* x     = (const float*)d_in[0];
    const int*   ei    = (const int*)d_in[1];
    const float* eattr = (const float*)d_in[2];
    const int*   dist  = (const int*)d_in[3];
    const float* W_l   = (const float*)d_in[4];
    const float* b_l   = (const float*)d_in[5];
    const float* W_r   = (const float*)d_in[6];
    const float* b_r   = (const float*)d_in[7];
    const float* W_e   = (const float*)d_in[8];
    const float* att   = (const float*)d_in[9];
    const float* bias  = (const float*)d_in[10];
    const float* gamma = (const float*)d_in[11];
    const float* beta  = (const float*)d_in[12];
    const float* W_res = (const float*)d_in[13];
    const float* b_res = (const float*)d_in[14];
    const float* bph   = (const float*)d_in[15];

    int n  = in_sizes[0] / 64;
    int E_ = in_sizes[1] / 2;
    float* out = (float*)d_out;

    char* ws = (char*)d_ws;
    float* xl     = (float*)ws; ws += (size_t)n * 64 * 4;
    float* xr     = (float*)ws; ws += (size_t)n * 64 * 4;
    int2*  bucket = (int2*)ws;  ws += (size_t)n * BUCKET * 8;
    int*   counts = (int*)ws;   ws += (size_t)n * 4;

    hipMemsetAsync(counts, 0, (size_t)n * 4, stream);
    prep<<<2048, 256, 0, stream>>>(x, W_l, b_l, W_r, b_r, W_res, b_res, W_e,
                                   dist, bph, xl, xr, out, ei, counts, bucket, n, E_);
    fused_gather<<<4096, 256, 0, stream>>>(counts, bucket, eattr,
                                           W_e, att, xl, xr,
                                           bias, gamma, beta, out, n);
}

// Round 22
// 243.741 us; speedup vs baseline: 2.1182x; 1.1544x over previous
//
#include <hip/hip_runtime.h>
#include <math.h>

#define NEG_SLOPE 0.2f
#define LN_EPS 1e-5f
#define BUCKET 48

typedef __attribute__((ext_vector_type(2))) float f32x2;

// DPP-based add: x += x permuted by CTRL (within 16-lane rows)
template <int CTRL>
__device__ __forceinline__ float dpp_add(float x) {
    int s = __builtin_amdgcn_update_dpp(0, __float_as_int(x), CTRL, 0xF, 0xF, true);
    return x + __int_as_float(s);
}
// full 16-lane row sum
__device__ __forceinline__ float row16_sum(float x) {
    x = dpp_add<0xB1>(x);   // quad_perm [1,0,3,2]
    x = dpp_add<0x4E>(x);   // quad_perm [2,3,0,1]
    x = dpp_add<0x124>(x);  // row_ror:4
    x = dpp_add<0x128>(x);  // row_ror:8
    return x;
}

// ---------- prep (FROZEN): transforms + hop-bias fold + direct bucket placement ------
__global__ __launch_bounds__(256) void prep(
    const float* __restrict__ x,
    const float* __restrict__ W_l, const float* __restrict__ b_l,
    const float* __restrict__ W_r, const float* __restrict__ b_r,
    const float* __restrict__ W_res, const float* __restrict__ b_res,
    const float* __restrict__ W_e,
    const int* __restrict__ dist, const float* __restrict__ bph,
    float* __restrict__ xl, float* __restrict__ xr, float* __restrict__ xres_out,
    const int* __restrict__ ei, int* __restrict__ counts, int2* __restrict__ bucket,
    int n, int E_) {
    __shared__ float sWl[4096];
    __shared__ float sWr[4096];
    __shared__ float sWs[4096];
    __shared__ float sx[256];
    for (int i = threadIdx.x; i < 4096; i += 256) {
        sWl[i] = W_l[i]; sWr[i] = W_r[i]; sWs[i] = W_res[i];
    }
    int lane = threadIdx.x & 63;
    int w = threadIdx.x >> 6;
    float bl = b_l[lane], br = b_r[lane], bs = b_res[lane];
    float wsum = 0.0f;
#pragma unroll
    for (int k = 0; k < 16; ++k) wsum += W_e[k * 64 + lane];
    __syncthreads();
    for (int base = blockIdx.x * 4; base < n; base += gridDim.x * 4) {
        __syncthreads();
        int r = base + w;
        if (r < n) sx[threadIdx.x] = x[(size_t)r * 64 + lane];
        __syncthreads();
        if (r < n) {
            float al = bl, ar = br, as_ = bs;
            const float* xv = &sx[w * 64];
#pragma unroll
            for (int k = 0; k < 64; ++k) {
                float xk = xv[k];
                al = fmaf(xk, sWl[k * 64 + lane], al);
                ar = fmaf(xk, sWr[k * 64 + lane], ar);
                as_ = fmaf(xk, sWs[k * 64 + lane], as_);
            }
            int hop = dist[r];
            hop = hop < 0 ? 0 : (hop > 3 ? 3 : hop);
            float hb = 0.1f * bph[hop];
            xl[(size_t)r * 64 + lane] = al;
            xr[(size_t)r * 64 + lane] = fmaf(hb, wsum, ar);  // hop bias folded in
            xres_out[(size_t)r * 64 + lane] = as_;           // residual staged in d_out
        }
    }
    // direct bucket placement
    const int* di = ei + E_;
    for (int e = blockIdx.x * 256 + threadIdx.x; e < E_; e += gridDim.x * 256) {
        int dst = di[e];
        int src = ei[e];
        int pos = atomicAdd(&counts[dst], 1);
        pos = pos < BUCKET - 1 ? pos : BUCKET - 1;  // safety clamp
        bucket[(size_t)dst * BUCKET + pos] = make_int2(e, src);
    }
}

// ---------- fused gather: 3-phase loop + NODE-LEVEL prologue prefetch ----------
#define LOAD_G(G, EA)                                                       \
    {                                                                       \
        int ec = __builtin_amdgcn_readfirstlane((EA).x);                    \
        const f32x2* p = (const f32x2*)(eattr + (size_t)ec * 16);           \
        _Pragma("unroll") for (int k = 0; k < 8; ++k) G[k] = p[k];          \
    }

#define PHASE(G, X, E, DEN, ACC, I)                                         \
    {                                                                       \
        f32x2 mm; mm.x = X + base; mm.y = 0.0f;                             \
        _Pragma("unroll") for (int k = 0; k < 8; ++k)                       \
            mm = __builtin_elementwise_fma(G[k], w2[k], mm);                \
        float m = mm.x + mm.y;                                              \
        m = fmaxf(m, NEG_SLOPE * m);                                        \
        float l = row16_sum(m * attv);   /* attv pre-scaled by log2(e) */   \
        l = (I) < cc ? l : -1e30f;                                          \
        float ex = __builtin_amdgcn_exp2f(l);                               \
        DEN += ex;                                                          \
        ACC = fmaf(ex, X, ACC);                                             \
        X = xl[((unsigned)(E).y << 6) | lane];                              \
        LOAD_G(G, E);                                                       \
        int nx = (I) + 6; nx = nx > last ? last : nx;                       \
        E = bk[nx];                                                         \
    }

__global__ __launch_bounds__(256) void fused_gather(
    const int* __restrict__ counts, const int2* __restrict__ bucket,
    const float* __restrict__ eattr,
    const float* __restrict__ W_e, const float* __restrict__ att,
    const float* __restrict__ xl, const float* __restrict__ xr,
    const float* __restrict__ bias,
    const float* __restrict__ gamma, const float* __restrict__ beta,
    float* out, int n) {
    int lane = threadIdx.x & 63;
    float attv = att[lane] * 1.44269504f;  // log2(e) folded: exp -> exp2
    float bi = bias[lane], g = gamma[lane], be = beta[lane];
    f32x2 w2[8];
#pragma unroll
    for (int k = 0; k < 8; ++k) {
        w2[k].x = W_e[(2 * k) * 64 + lane];
        w2[k].y = W_e[(2 * k + 1) * 64 + lane];
    }

    int wid = (blockIdx.x * blockDim.x + threadIdx.x) >> 6;
    int nw = (gridDim.x * blockDim.x) >> 6;
    if (wid >= n) return;
    int r = wid;
    // initial prologue prefetch for first node (unclamped slots 0..5: address-safe)
    int cnt = counts[r];
    float base = xr[((unsigned)r << 6) | lane];
    int2 A0, A1, A2, E0, E1, E2;
    {
        const int2* bkp = bucket + (size_t)r * BUCKET;
        A0 = bkp[0]; A1 = bkp[1]; A2 = bkp[2];
        E0 = bkp[3]; E1 = bkp[4]; E2 = bkp[5];
    }
    for (;;) {
        const int2* bk = bucket + (size_t)r * BUCKET;
        int cc = cnt < BUCKET ? cnt : BUCKET;
        int last = cc - 1;
        // sanitize prefetched entries (content clamp replaces old index clamp)
        int2 Z = make_int2(0, 0);
        A0 = cc > 0 ? A0 : Z;
        A1 = last >= 1 ? A1 : A0;
        A2 = last >= 2 ? A2 : A0;
        E0 = last >= 3 ? E0 : A0;
        E1 = last >= 4 ? E1 : A0;
        E2 = last >= 5 ? E2 : A0;
        // issue current node's X/G loads immediately (entries already in registers)
        float X0 = xl[((unsigned)A0.y << 6) | lane];
        float X1 = xl[((unsigned)A1.y << 6) | lane];
        float X2 = xl[((unsigned)A2.y << 6) | lane];
        f32x2 G0[8], G1[8], G2[8];
        LOAD_G(G0, A0);
        LOAD_G(G1, A1);
        LOAD_G(G2, A2);
        // prefetch next node's prologue (overlaps with this node's edge loop)
        int rn = r + nw;
        int hn = rn < n;
        int rc = hn ? rn : r;
        int cntn = counts[rc];
        float basen = xr[((unsigned)rc << 6) | lane];
        int2 An0, An1, An2, En0, En1, En2;
        {
            const int2* bkn = bucket + (size_t)rc * BUCKET;
            An0 = bkn[0]; An1 = bkn[1]; An2 = bkn[2];
            En0 = bkn[3]; En1 = bkn[4]; En2 = bkn[5];
        }
        // edge loop (proven R15 3-phase form)
        float den0 = 0.0f, den1 = 0.0f, den2 = 0.0f;
        float acc0 = 0.0f, acc1 = 0.0f, acc2 = 0.0f;
        for (int i = 0; i < cc; i += 3) {
            PHASE(G0, X0, E0, den0, acc0, i)
            PHASE(G1, X1, E1, den1, acc1, i + 1)
            PHASE(G2, X2, E2, den2, acc2, i + 2)
        }
        float den = (den0 + den1) + den2;
        float acc = (acc0 + acc1) + acc2;
        float v = acc / (den + 1e-16f) + bi;
        // LayerNorm over 64 features
        float s = row16_sum(v);
        s += __shfl_xor(s, 16, 64);
        s += __shfl_xor(s, 32, 64);
        float mu = s * (1.0f / 64.0f);
        float dd = v - mu;
        float q = row16_sum(dd * dd);
        q += __shfl_xor(q, 16, 64);
        q += __shfl_xor(q, 32, 64);
        float var = q * (1.0f / 64.0f);
        float nv = dd * rsqrtf(var + LN_EPS) * g + be;
        unsigned idx = ((unsigned)r << 6) | lane;
        out[idx] = nv + out[idx];  // residual was staged in out by prep
        if (!hn) break;
        // rotate prefetched state in
        r = rn; cnt = cntn; base = basen;
        A0 = An0; A1 = An1; A2 = An2;
        E0 = En0; E1 = En1; E2 = En2;
    }
}

extern "C" void kernel_launch(void* const* d_in, const int* in_sizes, int n_in,
                              void* d_out, int out_size, void* d_ws, size_t ws_size,
                              hipStream_t stream) {
    const float* x     = (const float*)d_in[0];
    const int*   ei    = (const int*)d_in[1];
    const float* eattr = (const float*)d_in[2];
    const int*   dist  = (const int*)d_in[3];
    const float* W_l   = (const float*)d_in[4];
    const float* b_l   = (const float*)d_in[5];
    const float* W_r   = (const float*)d_in[6];
    const float* b_r   = (const float*)d_in[7];
    const float* W_e   = (const float*)d_in[8];
    const float* att   = (const float*)d_in[9];
    const float* bias  = (const float*)d_in[10];
    const float* gamma = (const float*)d_in[11];
    const float* beta  = (const float*)d_in[12];
    const float* W_res = (const float*)d_in[13];
    const float* b_res = (const float*)d_in[14];
    const float* bph   = (const float*)d_in[15];

    int n  = in_sizes[0] / 64;
    int E_ = in_sizes[1] / 2;
    float* out = (float*)d_out;

    char* ws = (char*)d_ws;
    float* xl     = (float*)ws; ws += (size_t)n * 64 * 4;
    float* xr     = (float*)ws; ws += (size_t)n * 64 * 4;
    int2*  bucket = (int2*)ws;  ws += (size_t)n * BUCKET * 8;
    int*   counts = (int*)ws;   ws += (size_t)n * 4;

    hipMemsetAsync(counts, 0, (size_t)n * 4, stream);
    prep<<<2048, 256, 0, stream>>>(x, W_l, b_l, W_r, b_r, W_res, b_res, W_e,
                                   dist, bph, xl, xr, out, ei, counts, bucket, n, E_);
    fused_gather<<<4096, 256, 0, stream>>>(counts, bucket, eattr,
                                           W_e, att, xl, xr,
                                           bias, gamma, beta, out, n);
}